// Round 4
// baseline (751.255 us; speedup 1.0000x reference)
//
#include <hip/hip_runtime.h>
#include <math.h>

#define T_TOK 2048
#define H_DIM 2048
#define E_NUM 64
#define I_DIM 512
#define TOPK  6
#define NPAIR (T_TOK * TOPK)   // 12288

typedef __attribute__((ext_vector_type(8))) short s8;
typedef __attribute__((ext_vector_type(4))) float f4;
typedef __attribute__((ext_vector_type(8))) unsigned short u16x8;

static __device__ __forceinline__ unsigned short f2bf(float f) {
  unsigned int u = __float_as_uint(f);
  u += 0x7fff + ((u >> 16) & 1);          // RNE
  return (unsigned short)(u >> 16);
}
static __device__ __forceinline__ unsigned int cvt_pk(float lo, float hi) {
  unsigned int r;
  asm("v_cvt_pk_bf16_f32 %0, %1, %2" : "=v"(r) : "v"(lo), "v"(hi));
  return r;
}
static __device__ __forceinline__ void gload_lds16(const void* g, void* l) {
  __builtin_amdgcn_global_load_lds(
      (const __attribute__((address_space(1))) unsigned int*)g,
      (__attribute__((address_space(3))) unsigned int*)l, 16, 0, 0);
}
#define SBAR()   __builtin_amdgcn_s_barrier()
#define SCHED0() __builtin_amdgcn_sched_barrier(0)
#define WAIT_LGKM0() asm volatile("s_waitcnt lgkmcnt(0)" ::: "memory")
#define WAIT_VM(N)   asm volatile("s_waitcnt vmcnt(" #N ")" ::: "memory")

// ---------------- x fp32 -> bf16 ----------------
__global__ __launch_bounds__(256) void xconv_kernel(
    const float* __restrict__ x, unsigned short* __restrict__ xb)
{
  int i = (blockIdx.x * 256 + threadIdx.x) * 8;
  float4 a = *(const float4*)(x + i), b = *(const float4*)(x + i + 4);
  u16x8 p;
  ((unsigned int*)&p)[0] = cvt_pk(a.x, a.y);
  ((unsigned int*)&p)[1] = cvt_pk(a.z, a.w);
  ((unsigned int*)&p)[2] = cvt_pk(b.x, b.y);
  ((unsigned int*)&p)[3] = cvt_pk(b.z, b.w);
  *(u16x8*)(xb + i) = p;
}

// ---------------- Router: fp32 logits (4 tokens/block), softmax, top-6 selection ----------------
__global__ __launch_bounds__(256) void router_kernel(
    const float* __restrict__ x, const float* __restrict__ gw,
    const float* __restrict__ ebias, float* __restrict__ logits_out,
    int* __restrict__ sel, float* __restrict__ wsel)
{
  __shared__ float xs[4][H_DIM];   // 32 KB
  __shared__ float lg[4][E_NUM];
  int t0 = blockIdx.x * 4;
  int tid = threadIdx.x;
  for (int i = tid; i < 4 * (H_DIM / 4); i += 256) {
    int tt = i >> 9, q = i & 511;
    ((float4*)xs[tt])[q] = ((const float4*)(x + (size_t)(t0 + tt) * H_DIM))[q];
  }
  __syncthreads();

  int wave = tid >> 6, lane = tid & 63;
  for (int ei = 0; ei < 16; ++ei) {
    int e = wave * 16 + ei;
    const float4* gwe = (const float4*)(gw + (size_t)e * H_DIM);
    float s0 = 0.f, s1 = 0.f, s2 = 0.f, s3 = 0.f;
    for (int h4 = lane; h4 < H_DIM / 4; h4 += 64) {
      float4 w4 = gwe[h4];
      float4 a0 = ((const float4*)xs[0])[h4];
      float4 a1 = ((const float4*)xs[1])[h4];
      float4 a2 = ((const float4*)xs[2])[h4];
      float4 a3 = ((const float4*)xs[3])[h4];
      s0 += w4.x*a0.x + w4.y*a0.y + w4.z*a0.z + w4.w*a0.w;
      s1 += w4.x*a1.x + w4.y*a1.y + w4.z*a1.z + w4.w*a1.w;
      s2 += w4.x*a2.x + w4.y*a2.y + w4.z*a2.z + w4.w*a2.w;
      s3 += w4.x*a3.x + w4.y*a3.y + w4.z*a3.z + w4.w*a3.w;
    }
    for (int off = 32; off; off >>= 1) {
      s0 += __shfl_down(s0, off); s1 += __shfl_down(s1, off);
      s2 += __shfl_down(s2, off); s3 += __shfl_down(s3, off);
    }
    if (lane == 0) { lg[0][e] = s0; lg[1][e] = s1; lg[2][e] = s2; lg[3][e] = s3; }
  }
  __syncthreads();

  { int tt = tid >> 6, e = tid & 63;
    logits_out[(size_t)(t0 + tt) * E_NUM + e] = lg[tt][e]; }

  if (wave == 0) {
    for (int tt = 0; tt < 4; ++tt) {
      int t = t0 + tt;
      float v = lg[tt][lane];
      float m = v;
      for (int off = 32; off; off >>= 1) m = fmaxf(m, __shfl_xor(m, off));
      float ex = __expf(v - m);
      float sum = ex;
      for (int off = 32; off; off >>= 1) sum += __shfl_xor(sum, off);
      float prob = ex / sum;
      float sc = prob + ebias[lane];

      int selidx[TOPK]; float selw[TOPK]; float wsum = 0.f;
      #pragma unroll
      for (int k = 0; k < TOPK; ++k) {
        float mm = sc;
        for (int off = 32; off; off >>= 1) mm = fmaxf(mm, __shfl_xor(mm, off));
        unsigned long long ball = __ballot(sc == mm);
        int s = __ffsll(ball) - 1;          // lowest-index tie-break
        float p = __shfl(prob, s);          // weight from RAW prob
        selidx[k] = s; selw[k] = p; wsum += p;
        if (lane == s) sc = -INFINITY;
      }
      if (lane == 0) {
        float inv = 1.f / fmaxf(wsum, 1e-12f);
        #pragma unroll
        for (int k = 0; k < TOPK; ++k) {
          sel[t * TOPK + k] = selidx[k];
          wsel[t * TOPK + k] = selw[k] * inv;
        }
      }
    }
  }
}

// ---------------- Deterministic ordered per-expert lists ----------------
__global__ __launch_bounds__(64) void build_lists(
    const int* __restrict__ sel, const float* __restrict__ wsel,
    int* __restrict__ cnt, int* __restrict__ toklist, float* __restrict__ wtlist)
{
  int e = blockIdx.x, lane = threadIdx.x;
  int base = 0;
  for (int t0 = 0; t0 < T_TOK; t0 += 64) {
    int t = t0 + lane;
    int flag = 0; float w = 0.f;
    #pragma unroll
    for (int k = 0; k < TOPK; ++k)
      if (sel[t * TOPK + k] == e) { flag = 1; w = wsel[t * TOPK + k]; }
    unsigned long long b = __ballot(flag);
    int pos = base + __popcll(b & ((1ull << lane) - 1ull));
    if (flag) { toklist[e * T_TOK + pos] = t; wtlist[e * T_TOK + pos] = w; }
    base += __popcll(b);
  }
  if (lane == 0) cnt[e] = base;
}

__global__ void scan_kernel(const int* __restrict__ cnt, int* __restrict__ off) {
  if (threadIdx.x == 0) {
    int s = 0;
    for (int e = 0; e < E_NUM; ++e) { off[e] = s; s += cnt[e]; }
  }
}

// ---------------- gate/up GEMM + SwiGLU -> ha (bf16) ----------------
// 512 thr: waves 0-3 gate, 4-7 up. A via global_load_lds (bf16 x gather),
// B reg-staged depth-2. Raw barriers + counted vmcnt: loads span barriers.
__global__ __launch_bounds__(512, 4) void gateup_kernel(
    const unsigned short* __restrict__ xb, const float* __restrict__ gp,
    const float* __restrict__ up, const int* __restrict__ cnt,
    const int* __restrict__ off, const int* __restrict__ toklist,
    unsigned short* __restrict__ ha)
{
  __shared__ __align__(16) unsigned short A_lds[2][4 * 256 * 8];  // 2 x 16 KB [kg][row][8]
  __shared__ __align__(16) unsigned int   Bt[2][2][64 * 20];      // 2 x 10 KB
  int e = blockIdx.y, ic = blockIdx.x;
  int n = cnt[e];
  if (n == 0) return;
  int colbase = ic * 64;
  int tid = threadIdx.x, lane = tid & 63, wave = tid >> 6;
  int off_e = off[e];
  int matc = wave >> 2, cw = wave & 3;
  int lrow = (lane >> 4) * 4, lcol = lane & 15, kgl = lane >> 4;

  // B staging role
  int g8 = tid & 255, hp = g8 & 15, cb = g8 >> 4, mstage = tid >> 8;
  const float* bsrc0 = ((mstage == 0) ? gp : up)
      + (size_t)e * (H_DIM * I_DIM) + colbase + (size_t)(2 * hp) * I_DIM + cb * 4;

  // A staging role: wave covers rows rowgrp*64.., kg pair (kg0, kg0+1)
  int rowgrp = wave >> 1, kg0 = (wave & 1) * 2;

  for (int tb = 0; tb < n; tb += 256) {
    int tokrow = toklist[e * T_TOK + min(tb + rowgrp * 64 + lane, n - 1)];
    const unsigned short* asrc = xb + (size_t)tokrow * H_DIM + kg0 * 8;  // per-lane src

    float4 b0a, b0b, b1a, b1b;
    f4 acc[4][4];
    #pragma unroll
    for (int a = 0; a < 4; ++a)
      #pragma unroll
      for (int b = 0; b < 4; ++b) acc[a][b] = (f4)0.f;

    // prologue: A(0)->buf0, B(0)->BR0, B(1)->BR1, commit B(0)->buf0, full drain
    gload_lds16(asrc,     &A_lds[0][(kg0 * 256 + rowgrp * 64) * 8]);
    gload_lds16(asrc + 8, &A_lds[0][((kg0 + 1) * 256 + rowgrp * 64) * 8]);
    b0a = *(const float4*)bsrc0;
    b0b = *(const float4*)(bsrc0 + I_DIM);
    { const float* b = bsrc0 + 32 * I_DIM;
      b1a = *(const float4*)b; b1b = *(const float4*)(b + I_DIM); }
    { unsigned int* db = &Bt[0][mstage][cb * 4 * 20 + hp];
      db[0]  = cvt_pk(b0a.x, b0b.x); db[20] = cvt_pk(b0a.y, b0b.y);
      db[40] = cvt_pk(b0a.z, b0b.z); db[60] = cvt_pk(b0a.w, b0b.w); }
    __syncthreads();

#define GU_STEP(KS, BUF, CA, CB_, IA, IB) do {                                     \
    SCHED0();                                                                      \
    if ((KS) + 1 < 64) {  /* A(k+1) -> other buf via gld_lds */                    \
      const unsigned short* s = asrc + ((KS) + 1) * 32;                            \
      gload_lds16(s,     &A_lds[(BUF) ^ 1][(kg0 * 256 + rowgrp * 64) * 8]);        \
      gload_lds16(s + 8, &A_lds[(BUF) ^ 1][((kg0 + 1) * 256 + rowgrp * 64) * 8]);  \
    }                                                                              \
    SCHED0();                                                                      \
    if ((KS) + 2 < 64) {  /* B(k+2) -> issue regs */                               \
      const float* b = bsrc0 + (size_t)((KS) + 2) * 32 * I_DIM;                    \
      IA = *(const float4*)b; IB = *(const float4*)(b + I_DIM);                    \
    }                                                                              \
    SCHED0();                                                                      \
    {                                                                              \
      s8 afr[4];                                                                   \
      _Pragma("unroll")                                                            \
      for (int mf = 0; mf < 4; ++mf)                                               \
        afr[mf] = *(s8*)&A_lds[BUF][((kgl * 256) + cw * 64 + mf * 16 + lcol) * 8]; \
      _Pragma("unroll")                                                            \
      for (int nf = 0; nf < 4; ++nf) {                                             \
        s8 bfr = *(s8*)&Bt[BUF][matc][(nf * 16 + lcol) * 20 + kgl * 4];            \
        _Pragma("unroll")                                                          \
        for (int mf = 0; mf < 4; ++mf)                                             \
          acc[mf][nf] = __builtin_amdgcn_mfma_f32_16x16x32_bf16(afr[mf], bfr, acc[mf][nf], 0, 0, 0); \
      }                                                                            \
    }                                                                              \
    if ((KS) + 1 < 64) {  /* commit B(k+1) -> other buf */                         \
      unsigned int* db = &Bt[(BUF) ^ 1][mstage][cb * 4 * 20 + hp];                 \
      db[0]  = cvt_pk(CA.x, CB_.x); db[20] = cvt_pk(CA.y, CB_.y);                  \
      db[40] = cvt_pk(CA.z, CB_.z); db[60] = cvt_pk(CA.w, CB_.w);                  \
    }                                                                              \
    WAIT_LGKM0();                                                                  \
    if ((KS) + 2 < 64) { WAIT_VM(2); } else { WAIT_VM(0); }                        \
    SBAR();                                                                        \
    SCHED0();                                                                      \
  } while (0)

    for (int ks = 0; ks < 64; ks += 2) {
      GU_STEP(ks,     0, b1a, b1b, b0a, b0b);
      GU_STEP(ks + 1, 1, b0a, b0b, b1a, b1b);
    }
#undef GU_STEP

    // ---- SwiGLU epilogue: up waves ship U to gate waves via LDS (reuse A_lds[0]) ----
    f4* exch = (f4*)&A_lds[0][0];   // 1024 f4 = 16 KB
    #pragma unroll
    for (int nf = 0; nf < 4; ++nf) {
      __syncthreads();
      if (wave >= 4) {
        #pragma unroll
        for (int mf = 0; mf < 4; ++mf)
          exch[((wave - 4) * 4 + mf) * 64 + lane] = acc[mf][nf];
      }
      __syncthreads();
      if (wave < 4) {
        #pragma unroll
        for (int mf = 0; mf < 4; ++mf) {
          f4 u = exch[(wave * 4 + mf) * 64 + lane];
          #pragma unroll
          for (int j = 0; j < 4; ++j) {
            int r = wave * 64 + mf * 16 + lrow + j;
            if (tb + r < n) {
              float g = acc[mf][nf][j];
              float h = g / (1.f + __expf(-g)) * u[j];
              ha[(size_t)(off_e + tb + r) * I_DIM + colbase + nf * 16 + lcol] = f2bf(h);
            }
          }
        }
      }
    }
    __syncthreads();
  }
}

// ---------------- down GEMM + weighted atomic scatter ----------------
__global__ __launch_bounds__(256, 4) void down_kernel(
    const unsigned short* __restrict__ ha, const float* __restrict__ dp,
    const int* __restrict__ cnt, const int* __restrict__ off,
    const int* __restrict__ toklist, const float* __restrict__ wtlist,
    float* __restrict__ out)
{
  __shared__ __align__(16) unsigned short A_lds[2][4 * 256 * 8];  // 2 x 16 KB
  __shared__ __align__(16) unsigned int   Bt[2][64 * 20];         // 2 x 5 KB
  __shared__ int   stok[256];
  __shared__ float swt[256];
  int e = blockIdx.y, hc = blockIdx.x;
  int n = cnt[e];
  if (n == 0) return;
  int colbase = hc * 64;
  int tid = threadIdx.x, lane = tid & 63, wave = tid >> 6, wbase = wave * 64;
  int off_e = off[e];
  int hp = tid & 15, cb = tid >> 4;
  int lrow = (lane >> 4) * 4, lcol = lane & 15, kgl = lane >> 4;
  const float* bsrc0 = dp + (size_t)e * (I_DIM * H_DIM) + colbase
                       + (size_t)(2 * hp) * H_DIM + cb * 4;

  for (int tb = 0; tb < n; tb += 256) {
    __syncthreads();     // protect LDS reuse across tiles
    if (tb + tid < n) {
      stok[tid] = toklist[e * T_TOK + tb + tid];
      swt[tid]  = wtlist[e * T_TOK + tb + tid];
    }
    int rowg = min(off_e + tb + wbase + lane, NPAIR - 1);
    const unsigned short* arow = ha + (size_t)rowg * I_DIM;   // per-lane src

    float4 b0a, b0b, b1a, b1b;
    f4 acc[4][4];
    #pragma unroll
    for (int a = 0; a < 4; ++a)
      #pragma unroll
      for (int b = 0; b < 4; ++b) acc[a][b] = (f4)0.f;

    // prologue
    #pragma unroll
    for (int kg = 0; kg < 4; ++kg)
      gload_lds16(arow + kg * 8, &A_lds[0][(kg * 256 + wbase) * 8]);
    b0a = *(const float4*)bsrc0;
    b0b = *(const float4*)(bsrc0 + H_DIM);
    { const float* b = bsrc0 + 32 * H_DIM;
      b1a = *(const float4*)b; b1b = *(const float4*)(b + H_DIM); }
    { unsigned int* db = &Bt[0][cb * 4 * 20 + hp];
      db[0]  = cvt_pk(b0a.x, b0b.x); db[20] = cvt_pk(b0a.y, b0b.y);
      db[40] = cvt_pk(b0a.z, b0b.z); db[60] = cvt_pk(b0a.w, b0b.w); }
    __syncthreads();

#define DN_STEP(KS, BUF, CA, CB_, IA, IB) do {                                     \
    SCHED0();                                                                      \
    if ((KS) + 1 < 16) {                                                           \
      const unsigned short* s = arow + ((KS) + 1) * 32;                            \
      _Pragma("unroll")                                                            \
      for (int kg = 0; kg < 4; ++kg)                                               \
        gload_lds16(s + kg * 8, &A_lds[(BUF) ^ 1][(kg * 256 + wbase) * 8]);        \
    }                                                                              \
    SCHED0();                                                                      \
    if ((KS) + 2 < 16) {                                                           \
      const float* b = bsrc0 + (size_t)((KS) + 2) * 32 * H_DIM;                    \
      IA = *(const float4*)b; IB = *(const float4*)(b + H_DIM);                    \
    }                                                                              \
    SCHED0();                                                                      \
    {                                                                              \
      s8 afr[4];                                                                   \
      _Pragma("unroll")                                                            \
      for (int mf = 0; mf < 4; ++mf)                                               \
        afr[mf] = *(s8*)&A_lds[BUF][((kgl * 256) + wbase + mf * 16 + lcol) * 8];   \
      _Pragma("unroll")                                                            \
      for (int nf = 0; nf < 4; ++nf) {                                             \
        s8 bfr = *(s8*)&Bt[BUF][(nf * 16 + lcol) * 20 + kgl * 4];                  \
        _Pragma("unroll")                                                          \
        for (int mf = 0; mf < 4; ++mf)                                             \
          acc[mf][nf] = __builtin_amdgcn_mfma_f32_16x16x32_bf16(afr[mf], bfr, acc[mf][nf], 0, 0, 0); \
      }                                                                            \
    }                                                                              \
    if ((KS) + 1 < 16) {                                                           \
      unsigned int* db = &Bt[(BUF) ^ 1][cb * 4 * 20 + hp];                         \
      db[0]  = cvt_pk(CA.x, CB_.x); db[20] = cvt_pk(CA.y, CB_.y);                  \
      db[40] = cvt_pk(CA.z, CB_.z); db[60] = cvt_pk(CA.w, CB_.w);                  \
    }                                                                              \
    WAIT_LGKM0();                                                                  \
    if ((KS) + 2 < 16) { WAIT_VM(2); } else { WAIT_VM(0); }                        \
    SBAR();                                                                        \
    SCHED0();                                                                      \
  } while (0)

    for (int ks = 0; ks < 16; ks += 2) {
      DN_STEP(ks,     0, b1a, b1b, b0a, b0b);
      DN_STEP(ks + 1, 1, b0a, b0b, b1a, b1b);
    }
#undef DN_STEP

    #pragma unroll
    for (int mf = 0; mf < 4; ++mf)
      #pragma unroll
      for (int nf = 0; nf < 4; ++nf)
        #pragma unroll
        for (int j = 0; j < 4; ++j) {
          int r = wbase + mf * 16 + lrow + j;
          if (tb + r < n)
            atomicAdd(&out[(size_t)stok[r] * H_DIM + colbase + nf * 16 + lcol],
                      acc[mf][nf][j] * swt[r]);
        }
  }
}

extern "C" void kernel_launch(void* const* d_in, const int* in_sizes, int n_in,
                              void* d_out, int out_size, void* d_ws, size_t ws_size,
                              hipStream_t stream) {
  const float* hidden = (const float*)d_in[0];
  const float* gate_w = (const float*)d_in[1];
  const float* e_bias = (const float*)d_in[2];
  const float* gate_p = (const float*)d_in[3];
  const float* up_p   = (const float*)d_in[4];
  const float* down_p = (const float*)d_in[5];

  float* out_final  = (float*)d_out;                       // [T, H]
  float* out_logits = out_final + (size_t)T_TOK * H_DIM;   // [T, E]

  int*   cnt     = (int*)d_ws;
  int*   off     = cnt + 64;
  int*   sel     = off + 64;
  float* wsel    = (float*)(sel + T_TOK * TOPK);
  int*   toklist = (int*)(wsel + T_TOK * TOPK);
  float* wtlist  = (float*)(toklist + E_NUM * T_TOK);
  unsigned short* ha = (unsigned short*)(wtlist + E_NUM * T_TOK);  // 12288*512 bf16
  unsigned short* xb = ha + (size_t)NPAIR * I_DIM;                 // 2048*2048 bf16

  hipMemsetAsync(out_final, 0, (size_t)T_TOK * H_DIM * sizeof(float), stream);

  xconv_kernel<<<T_TOK * H_DIM / 8 / 256, 256, 0, stream>>>(hidden, xb);
  router_kernel<<<T_TOK / 4, 256, 0, stream>>>(hidden, gate_w, e_bias, out_logits, sel, wsel);
  build_lists<<<E_NUM, 64, 0, stream>>>(sel, wsel, cnt, toklist, wtlist);
  scan_kernel<<<1, 64, 0, stream>>>(cnt, off);
  gateup_kernel<<<dim3(I_DIM / 64, E_NUM), 512, 0, stream>>>(
      xb, gate_p, up_p, cnt, off, toklist, ha);
  down_kernel<<<dim3(H_DIM / 64, E_NUM), 256, 0, stream>>>(
      ha, down_p, cnt, off, toklist, wtlist, out_final);
}